// Round 2
// baseline (6247.898 us; speedup 1.0000x reference)
//
#include <hip/hip_runtime.h>
#include <hip/hip_bf16.h>

// Problem constants (from reference)
constexpr int kB   = 4;
constexpr int kNEG = 33;
constexpr int kN   = 10000;
constexpr int kR   = 256;
constexpr int kD   = 64;
constexpr int kL   = 6;
constexpr int kE   = 200000;
constexpr int kER  = 80000;
constexpr int kF   = 128;

typedef const float* fp;

__device__ __forceinline__ float wave_sum64(float v) {
  #pragma unroll
  for (int o = 32; o > 0; o >>= 1) v += __shfl_xor(v, o, 64);
  return v;
}

// ---------------- utility kernels ----------------

__global__ void k_fill(float* __restrict__ p, float v, int n) {
  int i = blockIdx.x * blockDim.x + threadIdx.x;
  int stride = gridDim.x * blockDim.x;
  for (; i < n; i += stride) p[i] = v;
}

// dst[b, row(b), d] += (q ? q[b,d] : 1.0)   ; row = batch[b,0,2] (mode 0) or batch[b,0,0] (mode 1)
__global__ void k_add_row(float* __restrict__ dst, const int* __restrict__ batch,
                          const float* __restrict__ q, int M, int mode) {
  int tid = threadIdx.x;            // 256 threads
  int b = tid >> 6, d = tid & 63;
  int row = (mode == 0) ? batch[b * kNEG * 3 + 2] : batch[b * kNEG * 3 + 0];
  float v = q ? q[b * 64 + d] : 1.0f;
  dst[((size_t)b * M + row) * 64 + d] += v;
}

// q[b,d] = relx[b, r0(b), d]
__global__ void k_get_q(float* __restrict__ q, const float* __restrict__ relx,
                        const int* __restrict__ batch) {
  int tid = threadIdx.x;            // 256 threads
  int b = tid >> 6, d = tid & 63;
  int r0 = batch[b * kNEG * 3 + 2];
  q[b * 64 + d] = relx[((size_t)b * kR + r0) * 64 + d];
}

__global__ void k_axpy(float* __restrict__ x, const float* __restrict__ h, int n) {
  int i = blockIdx.x * blockDim.x + threadIdx.x;
  if (i < n) x[i] += h[i];
}

// ---------------- gate MLP: out = relu(in @ W1 + b1) @ W2 + b2 ----------------
// one wave per row, lane j owns output column j
__global__ void k_mlp(const float* __restrict__ in, fp W1, fp b1, fp W2, fp b2,
                      float* __restrict__ out, int rows) {
  int wid = (blockIdx.x * blockDim.x + threadIdx.x) >> 6;
  int lane = threadIdx.x & 63;
  if (wid >= rows) return;
  float xv = in[(size_t)wid * 64 + lane];
  float acc = b1[lane];
  #pragma unroll 16
  for (int k = 0; k < 64; ++k)
    acc = fmaf(__shfl(xv, k, 64), W1[k * 64 + lane], acc);
  float h = fmaxf(acc, 0.f);
  float acc2 = b2[lane];
  #pragma unroll 16
  for (int k = 0; k < 64; ++k)
    acc2 = fmaf(__shfl(h, k, 64), W2[k * 64 + lane], acc2);
  out[(size_t)wid * 64 + lane] = acc2;
}

// ---------------- edge scatter: agg[b,dst,:] += x[b,src,:] * gate[b,et,:] ----------------
// one wave per edge (64 lanes = 64 channels), loop over batch
__global__ void k_scatter(const float* __restrict__ x, const float* __restrict__ gate,
                          const int* __restrict__ src, const int* __restrict__ dst,
                          const int* __restrict__ et, float* __restrict__ agg,
                          int ne, int M, int G) {
  int gid = blockIdx.x * blockDim.x + threadIdx.x;
  int e = gid >> 6, d = gid & 63;
  if (e >= ne) return;
  int s = src[e], dr = dst[e], t = et[e];
  const float* xp = x + (size_t)s * 64 + d;
  const float* gp = gate + (size_t)t * 64 + d;
  float* ap = agg + (size_t)dr * 64 + d;
  #pragma unroll
  for (int b = 0; b < kB; ++b) {
    float v = xp[(size_t)b * M * 64] * gp[(size_t)b * G * 64];
    atomicAdd(ap + (size_t)b * M * 64, v);
  }
}

// ---------------- conv output: dst += relu(LN(concat(x,agg) @ lw + lb)) ----------------
__global__ void k_conv_out(const float* __restrict__ x, const float* __restrict__ agg,
                           fp lw, fp lb, fp lns, fp lnb,
                           float* __restrict__ dst, int rows) {
  int wid = (blockIdx.x * blockDim.x + threadIdx.x) >> 6;
  int lane = threadIdx.x & 63;
  if (wid >= rows) return;
  float xv = x[(size_t)wid * 64 + lane];
  float av = agg[(size_t)wid * 64 + lane];
  float acc = lb[lane];
  #pragma unroll 16
  for (int k = 0; k < 64; ++k)
    acc = fmaf(__shfl(xv, k, 64), lw[k * 64 + lane], acc);
  #pragma unroll 16
  for (int k = 0; k < 64; ++k)
    acc = fmaf(__shfl(av, k, 64), lw[(64 + k) * 64 + lane], acc);
  float m = wave_sum64(acc) * (1.f / 64.f);
  float c = acc - m;
  float v = wave_sum64(c * c) * (1.f / 64.f);
  float y = c * rsqrtf(v + 1e-5f) * lns[lane] + lnb[lane];
  dst[(size_t)wid * 64 + lane] += fmaxf(y, 0.f);
}

// ---------------- node_reps = concat(ent_x, q) @ nmw + nmb ----------------
__global__ void k_nodeup(const float* __restrict__ x, const float* __restrict__ q,
                         fp nmw, fp nmb, float* __restrict__ out, int rows) {
  int wid = (blockIdx.x * blockDim.x + threadIdx.x) >> 6;
  int lane = threadIdx.x & 63;
  if (wid >= rows) return;
  int b = wid / kN;
  float xv = x[(size_t)wid * 64 + lane];
  float qv = q[b * 64 + lane];
  float acc = nmb[lane];
  #pragma unroll 16
  for (int k = 0; k < 64; ++k)
    acc = fmaf(__shfl(xv, k, 64), nmw[k * 64 + lane], acc);
  #pragma unroll 16
  for (int k = 0; k < 64; ++k)
    acc = fmaf(__shfl(qv, k, 64), nmw[(64 + k) * 64 + lane], acc);
  out[(size_t)wid * 64 + lane] = acc;
}

// ---------------- final scoring ----------------
// one block (128 threads) per (b, n); g = concat(ent_x[b, t], q[b])
__global__ void k_score(const float* __restrict__ entx, const float* __restrict__ q,
                        const int* __restrict__ batch,
                        fp m1w, fp m1b, fp m2w, fp m2b,
                        float* __restrict__ out) {
  int b = blockIdx.x / kNEG, n = blockIdx.x % kNEG;
  int t = batch[(b * kNEG + n) * 3 + 1];
  int j = threadIdx.x;  // 0..127
  __shared__ float gv[128];
  __shared__ float red[2];
  gv[j] = (j < 64) ? entx[((size_t)b * kN + t) * 64 + j] : q[b * 64 + (j - 64)];
  __syncthreads();
  float acc = m1b[j];
  #pragma unroll 16
  for (int k = 0; k < 128; ++k)
    acc = fmaf(gv[k], m1w[k * 128 + j], acc);
  float h = fmaxf(acc, 0.f) * m2w[j];
  h = wave_sum64(h);
  if ((j & 63) == 0) red[j >> 6] = h;
  __syncthreads();
  if (j == 0) out[b * kNEG + n] = red[0] + red[1] + m2b[0];
}

// ---------------- host orchestration ----------------

static inline void fill_async(float* p, float v, int n, hipStream_t s) {
  int nb = (n + 255) / 256;
  if (nb > 8192) nb = 8192;
  hipLaunchKernelGGL(k_fill, dim3(nb), dim3(256), 0, s, p, v, n);
}

extern "C" void kernel_launch(void* const* d_in, const int* in_sizes, int n_in,
                              void* d_out, int out_size, void* d_ws, size_t ws_size,
                              hipStream_t stream) {
  const int* edge_src  = (const int*)d_in[0];
  const int* edge_dst  = (const int*)d_in[1];
  const int* edge_type = (const int*)d_in[2];
  const int* rel_src   = (const int*)d_in[3];
  const int* rel_dst   = (const int*)d_in[4];
  const int* rel_etype = (const int*)d_in[5];
  const int* batch     = (const int*)d_in[6];
  fp e1p1w = (fp)d_in[7],  e1p1b = (fp)d_in[8],  e1p2w = (fp)d_in[9],  e1p2b = (fp)d_in[10];
  fp e1lw  = (fp)d_in[11], e1lb  = (fp)d_in[12], e1lns = (fp)d_in[13], e1lnb = (fp)d_in[14];
  fp e2p1w = (fp)d_in[15], e2p1b = (fp)d_in[16], e2p2w = (fp)d_in[17], e2p2b = (fp)d_in[18];
  fp e2lw  = (fp)d_in[19], e2lb  = (fp)d_in[20], e2lns = (fp)d_in[21], e2lnb = (fp)d_in[22];
  fp e2m1w = (fp)d_in[23], e2m1b = (fp)d_in[24], e2m2w = (fp)d_in[25], e2m2b = (fp)d_in[26];
  fp rp1w  = (fp)d_in[27], rp1b  = (fp)d_in[28], rp2w  = (fp)d_in[29], rp2b  = (fp)d_in[30];
  fp rlw   = (fp)d_in[31], rlb   = (fp)d_in[32], rlns  = (fp)d_in[33], rlnb  = (fp)d_in[34];
  fp nmw   = (fp)d_in[35], nmb   = (fp)d_in[36];

  float* ws = (float*)d_ws;
  float* rel_x     = ws;                       // B*R*D = 65536
  float* rel_h     = rel_x + 65536;            // 65536
  float* rel_agg   = rel_h + 65536;            // 65536
  float* q         = rel_agg + 65536;          // 256
  float* gateR     = q + 256;                  // 65536
  float* node_reps = gateR + 65536;            // B*N*D = 2,560,000
  float* gateN     = node_reps + 2560000;      // 2,560,000
  float* ent_x     = gateN + 2560000;          // 2,560,000
  float* ent_agg   = ent_x + 2560000;          // 2,560,000

  const int nRelRows = kB * kR;   // 1024
  const int nEntRows = kB * kN;   // 40000

  // node_reps = ones ; rel_x = one-hot boundary
  fill_async(node_reps, 1.0f, kB * kN * kD, stream);
  fill_async(rel_x, 0.0f, kB * kR * kD, stream);
  hipLaunchKernelGGL(k_add_row, dim3(1), dim3(256), 0, stream, rel_x, batch, (const float*)nullptr, kR, 0);

  for (int i = 0; i < kL; ++i) {
    fill_async(rel_h, 0.0f, kB * kR * kD, stream);
    for (int g = 0; g < 4; ++g) {
      int pg = g * kL + i;
      hipLaunchKernelGGL(k_mlp, dim3(nEntRows / 4), dim3(256), 0, stream,
                         node_reps, rp1w + (size_t)pg * 4096, rp1b + (size_t)pg * 64,
                         rp2w + (size_t)pg * 4096, rp2b + (size_t)pg * 64, gateN, nEntRows);
      fill_async(rel_agg, 0.0f, kB * kR * kD, stream);
      hipLaunchKernelGGL(k_scatter, dim3((kER * 64) / 256), dim3(256), 0, stream,
                         rel_x, gateN, rel_src + (size_t)g * kER, rel_dst + (size_t)g * kER,
                         rel_etype + (size_t)g * kER, rel_agg, kER, kR, kN);
      hipLaunchKernelGGL(k_add_row, dim3(1), dim3(256), 0, stream, rel_agg, batch, (const float*)nullptr, kR, 0);
      hipLaunchKernelGGL(k_conv_out, dim3(nRelRows / 4), dim3(256), 0, stream,
                         rel_x, rel_agg, rlw + (size_t)pg * 8192, rlb + (size_t)pg * 64,
                         rlns + (size_t)pg * 64, rlnb + (size_t)pg * 64, rel_h, nRelRows);
    }
    hipLaunchKernelGGL(k_axpy, dim3(kB * kR * kD / 256), dim3(256), 0, stream, rel_x, rel_h, kB * kR * kD);

    if (i == 0) {
      // entity_bf with e1 params -> node_reps
      hipLaunchKernelGGL(k_get_q, dim3(1), dim3(256), 0, stream, q, rel_x, batch);
      fill_async(ent_x, 0.0f, kB * kN * kD, stream);
      hipLaunchKernelGGL(k_add_row, dim3(1), dim3(256), 0, stream, ent_x, batch, q, kN, 1);
      for (int j = 0; j < kL; ++j) {
        hipLaunchKernelGGL(k_mlp, dim3(nRelRows / 4), dim3(256), 0, stream,
                           rel_x, e1p1w + (size_t)j * 4096, e1p1b + (size_t)j * 64,
                           e1p2w + (size_t)j * 4096, e1p2b + (size_t)j * 64, gateR, nRelRows);
        fill_async(ent_agg, 0.0f, kB * kN * kD, stream);
        hipLaunchKernelGGL(k_scatter, dim3((kE * 64) / 256), dim3(256), 0, stream,
                           ent_x, gateR, edge_src, edge_dst, edge_type, ent_agg, kE, kN, kR);
        hipLaunchKernelGGL(k_add_row, dim3(1), dim3(256), 0, stream, ent_agg, batch, q, kN, 1);
        hipLaunchKernelGGL(k_conv_out, dim3(nEntRows / 4), dim3(256), 0, stream,
                           ent_x, ent_agg, e1lw + (size_t)j * 8192, e1lb + (size_t)j * 64,
                           e1lns + (size_t)j * 64, e1lnb + (size_t)j * 64, ent_x, nEntRows);
      }
      hipLaunchKernelGGL(k_nodeup, dim3(nEntRows / 4), dim3(256), 0, stream,
                         ent_x, q, nmw, nmb, node_reps, nEntRows);
    }
  }

  // entity_bf with e2 params -> final ent_x, then scoring
  hipLaunchKernelGGL(k_get_q, dim3(1), dim3(256), 0, stream, q, rel_x, batch);
  fill_async(ent_x, 0.0f, kB * kN * kD, stream);
  hipLaunchKernelGGL(k_add_row, dim3(1), dim3(256), 0, stream, ent_x, batch, q, kN, 1);
  for (int j = 0; j < kL; ++j) {
    hipLaunchKernelGGL(k_mlp, dim3(nRelRows / 4), dim3(256), 0, stream,
                       rel_x, e2p1w + (size_t)j * 4096, e2p1b + (size_t)j * 64,
                       e2p2w + (size_t)j * 4096, e2p2b + (size_t)j * 64, gateR, nRelRows);
    fill_async(ent_agg, 0.0f, kB * kN * kD, stream);
    hipLaunchKernelGGL(k_scatter, dim3((kE * 64) / 256), dim3(256), 0, stream,
                       ent_x, gateR, edge_src, edge_dst, edge_type, ent_agg, kE, kN, kR);
    hipLaunchKernelGGL(k_add_row, dim3(1), dim3(256), 0, stream, ent_agg, batch, q, kN, 1);
    hipLaunchKernelGGL(k_conv_out, dim3(nEntRows / 4), dim3(256), 0, stream,
                       ent_x, ent_agg, e2lw + (size_t)j * 8192, e2lb + (size_t)j * 64,
                       e2lns + (size_t)j * 64, e2lnb + (size_t)j * 64, ent_x, nEntRows);
  }
  hipLaunchKernelGGL(k_score, dim3(kB * kNEG), dim3(128), 0, stream,
                     ent_x, q, batch, e2m1w, e2m1b, e2m2w, e2m2b, (float*)d_out);
}

// Round 3
// 2479.318 us; speedup vs baseline: 2.5200x; 2.5200x over previous
//
#include <hip/hip_runtime.h>
#include <hip/hip_bf16.h>

constexpr int kB   = 4;
constexpr int kNEG = 33;
constexpr int kN   = 10000;
constexpr int kR   = 256;
constexpr int kD   = 64;
constexpr int kL   = 6;
constexpr int kE   = 200000;
constexpr int kER  = 80000;

typedef const float* fp;

__device__ __forceinline__ float rdlane(float v, int l) {
  return __uint_as_float(__builtin_amdgcn_readlane(__float_as_uint(v), l));
}
__device__ __forceinline__ float wave_sum64(float v) {
  #pragma unroll
  for (int o = 32; o > 0; o >>= 1) v += __shfl_xor(v, o, 64);
  return v;
}

// ---------------- utility ----------------
__global__ void k_fill(float* __restrict__ p, float v, int n) {
  int i = blockIdx.x * blockDim.x + threadIdx.x;
  int stride = gridDim.x * blockDim.x;
  for (; i < n; i += stride) p[i] = v;
}
__global__ void k_zero_i(int* __restrict__ p, int n) {
  int i = blockIdx.x * blockDim.x + threadIdx.x;
  if (i < n) p[i] = 0;
}
// dst[b,row(b),d] += (q ? q[b,d] : 1.0)
__global__ void k_add_row(float* __restrict__ dst, const int* __restrict__ batch,
                          const float* __restrict__ q, int M, int mode) {
  int tid = threadIdx.x;
  int b = tid >> 6, d = tid & 63;
  int row = (mode == 0) ? batch[b * kNEG * 3 + 2] : batch[b * kNEG * 3 + 0];
  float v = q ? q[b * 64 + d] : 1.0f;
  dst[((size_t)b * M + row) * 64 + d] += v;
}
__global__ void k_get_q(float* __restrict__ q, const float* __restrict__ relx,
                        const int* __restrict__ batch) {
  int tid = threadIdx.x;
  int b = tid >> 6, d = tid & 63;
  int r0 = batch[b * kNEG * 3 + 2];
  q[b * 64 + d] = relx[((size_t)b * kR + r0) * 64 + d];
}
__global__ void k_axpy(float* __restrict__ x, const float* __restrict__ h, int n) {
  int i = blockIdx.x * blockDim.x + threadIdx.x;
  if (i < n) x[i] += h[i];
}

// ---------------- CSR build ----------------
__global__ void k_hist(const int* __restrict__ dst, int ne, int* __restrict__ cnt) {
  int i = blockIdx.x * blockDim.x + threadIdx.x;
  if (i < ne) atomicAdd(&cnt[dst[i]], 1);
}
// exclusive scan of cnt[0..n) -> start[0..n], cursor copy. single block 256 threads.
__global__ void k_scan(const int* __restrict__ cnt, int* __restrict__ start,
                       int* __restrict__ cursor, int n) {
  __shared__ int part[256];
  int t = threadIdx.x;
  int chunk = (n + 255) / 256;
  int lo = t * chunk, hi = min(lo + chunk, n);
  int s = 0;
  for (int i = lo; i < hi; ++i) s += cnt[i];
  part[t] = s;
  __syncthreads();
  if (t == 0) { int run = 0; for (int i = 0; i < 256; ++i) { int v = part[i]; part[i] = run; run += v; } }
  __syncthreads();
  int run = part[t];
  for (int i = lo; i < hi; ++i) { start[i] = run; cursor[i] = run; run += cnt[i]; }
  if (t == 255) start[n] = run;
}
__global__ void k_fill_csr(const int* __restrict__ src, const int* __restrict__ dst,
                           const int* __restrict__ et, int ne,
                           int* __restrict__ cursor, int2* __restrict__ out) {
  int i = blockIdx.x * blockDim.x + threadIdx.x;
  if (i < ne) {
    int p = atomicAdd(&cursor[dst[i]], 1);
    out[p] = make_int2(src[i], et[i]);
  }
}

// ---------------- 4-row MLP: out = relu(in@W1+b1)@W2+b2 ----------------
__global__ void k_mlp4(const float* __restrict__ in, fp W1, fp b1, fp W2, fp b2,
                       float* __restrict__ out, int rows) {
  int wid = (blockIdx.x * blockDim.x + threadIdx.x) >> 6;
  int lane = threadIdx.x & 63;
  int r0 = wid * 4;
  if (r0 >= rows) return;
  const float* ip = in + (size_t)r0 * 64 + lane;
  float x0 = ip[0], x1 = ip[64], x2 = ip[128], x3 = ip[192];
  float bv = b1[lane];
  float a0 = bv, a1 = bv, a2 = bv, a3 = bv;
  #pragma unroll
  for (int k = 0; k < 64; ++k) {
    float w = W1[k * 64 + lane];
    a0 = fmaf(rdlane(x0, k), w, a0); a1 = fmaf(rdlane(x1, k), w, a1);
    a2 = fmaf(rdlane(x2, k), w, a2); a3 = fmaf(rdlane(x3, k), w, a3);
  }
  a0 = fmaxf(a0, 0.f); a1 = fmaxf(a1, 0.f); a2 = fmaxf(a2, 0.f); a3 = fmaxf(a3, 0.f);
  bv = b2[lane];
  float c0 = bv, c1 = bv, c2 = bv, c3 = bv;
  #pragma unroll
  for (int k = 0; k < 64; ++k) {
    float w = W2[k * 64 + lane];
    c0 = fmaf(rdlane(a0, k), w, c0); c1 = fmaf(rdlane(a1, k), w, c1);
    c2 = fmaf(rdlane(a2, k), w, c2); c3 = fmaf(rdlane(a3, k), w, c3);
  }
  float* op = out + (size_t)r0 * 64 + lane;
  op[0] = c0; op[64] = c1; op[128] = c2; op[192] = c3;
}

// ---------------- 4-row conv: dst += relu(LN(concat(x,agg)@lw+lb)) ----------------
__global__ void k_conv4(const float* __restrict__ x, const float* __restrict__ agg,
                        fp lw, fp lb, fp lns, fp lnb,
                        float* __restrict__ dst, int rows) {
  int wid = (blockIdx.x * blockDim.x + threadIdx.x) >> 6;
  int lane = threadIdx.x & 63;
  int r0 = wid * 4;
  if (r0 >= rows) return;
  const float* xp = x + (size_t)r0 * 64 + lane;
  const float* ap = agg + (size_t)r0 * 64 + lane;
  float x0 = xp[0], x1 = xp[64], x2 = xp[128], x3 = xp[192];
  float g0 = ap[0], g1 = ap[64], g2 = ap[128], g3 = ap[192];
  float bv = lb[lane];
  float o0 = bv, o1 = bv, o2 = bv, o3 = bv;
  #pragma unroll
  for (int k = 0; k < 64; ++k) {
    float w = lw[k * 64 + lane];
    o0 = fmaf(rdlane(x0, k), w, o0); o1 = fmaf(rdlane(x1, k), w, o1);
    o2 = fmaf(rdlane(x2, k), w, o2); o3 = fmaf(rdlane(x3, k), w, o3);
  }
  #pragma unroll
  for (int k = 0; k < 64; ++k) {
    float w = lw[(64 + k) * 64 + lane];
    o0 = fmaf(rdlane(g0, k), w, o0); o1 = fmaf(rdlane(g1, k), w, o1);
    o2 = fmaf(rdlane(g2, k), w, o2); o3 = fmaf(rdlane(g3, k), w, o3);
  }
  float s = lns[lane], t = lnb[lane];
  float* dp = dst + (size_t)r0 * 64 + lane;
  {
    float m = wave_sum64(o0) * (1.f / 64.f); float c = o0 - m;
    float v = wave_sum64(c * c) * (1.f / 64.f);
    dp[0] += fmaxf(c * rsqrtf(v + 1e-5f) * s + t, 0.f);
  }
  {
    float m = wave_sum64(o1) * (1.f / 64.f); float c = o1 - m;
    float v = wave_sum64(c * c) * (1.f / 64.f);
    dp[64] += fmaxf(c * rsqrtf(v + 1e-5f) * s + t, 0.f);
  }
  {
    float m = wave_sum64(o2) * (1.f / 64.f); float c = o2 - m;
    float v = wave_sum64(c * c) * (1.f / 64.f);
    dp[128] += fmaxf(c * rsqrtf(v + 1e-5f) * s + t, 0.f);
  }
  {
    float m = wave_sum64(o3) * (1.f / 64.f); float c = o3 - m;
    float v = wave_sum64(c * c) * (1.f / 64.f);
    dp[192] += fmaxf(c * rsqrtf(v + 1e-5f) * s + t, 0.f);
  }
}

// ---------------- entity gather: agg[b,dst,:] = sum_e x[b,src,:]*gate[b,et,:] (+boundary) ----------------
__global__ void k_gather_ent(const float* __restrict__ x, const float* __restrict__ gate,
                             const int* __restrict__ start, const int2* __restrict__ edges,
                             const float* __restrict__ q, const int* __restrict__ batch,
                             float* __restrict__ agg) {
  int wid = (blockIdx.x * blockDim.x + threadIdx.x) >> 6;  // b*kN + dst
  if (wid >= kB * kN) return;
  int lane = threadIdx.x & 63;
  int b = wid / kN, dstn = wid - b * kN;
  const float* xb = x + (size_t)b * kN * 64 + lane;
  const float* gb = gate + (size_t)b * kR * 64 + lane;
  int s0 = start[dstn], s1 = start[dstn + 1];
  float acc = 0.f;
  #pragma unroll 4
  for (int e = s0; e < s1; ++e) {
    int2 se = edges[e];
    acc = fmaf(xb[(size_t)se.x * 64], gb[(size_t)se.y * 64], acc);
  }
  int h0 = batch[b * kNEG * 3];
  if (dstn == h0) acc += q[b * 64 + lane];
  agg[(size_t)wid * 64 + lane] = acc;
}

// ---------------- rel gather: one block per (b,dst), 4-wave segmented ----------------
__global__ void k_gather_rel(const float* __restrict__ x, const float* __restrict__ gate,
                             const int* __restrict__ start, const int2* __restrict__ edges,
                             const int* __restrict__ batch,
                             float* __restrict__ agg) {
  int blk = blockIdx.x;              // b*kR + dst
  int b = blk / kR, dstn = blk - b * kR;
  int w = threadIdx.x >> 6, lane = threadIdx.x & 63;
  const float* xb = x + (size_t)b * kR * 64 + lane;
  const float* gb = gate + (size_t)b * kN * 64 + lane;
  int s0 = start[dstn], s1 = start[dstn + 1];
  int len = s1 - s0;
  int per = (len + 3) >> 2;
  int e0 = s0 + w * per, e1 = min(e0 + per, s1);
  float acc = 0.f;
  #pragma unroll 4
  for (int e = e0; e < e1; ++e) {
    int2 se = edges[e];
    acc = fmaf(xb[(size_t)se.x * 64], gb[(size_t)se.y * 64], acc);
  }
  __shared__ float red[4][64];
  red[w][lane] = acc;
  __syncthreads();
  if (w == 0) {
    float a = red[0][lane] + red[1][lane] + red[2][lane] + red[3][lane];
    int r0 = batch[b * kNEG * 3 + 2];
    if (dstn == r0) a += 1.0f;
    agg[(size_t)blk * 64 + lane] = a;
  }
}

// ---------------- node_reps = concat(ent_x, q)@nmw + nmb (4-row) ----------------
__global__ void k_nodeup4(const float* __restrict__ x, const float* __restrict__ q,
                          fp nmw, fp nmb, float* __restrict__ out, int rows) {
  int wid = (blockIdx.x * blockDim.x + threadIdx.x) >> 6;
  int lane = threadIdx.x & 63;
  int r0 = wid * 4;
  if (r0 >= rows) return;
  int b = r0 / kN;                     // kN % 4 == 0 -> all 4 rows same b
  const float* ip = x + (size_t)r0 * 64 + lane;
  float x0 = ip[0], x1 = ip[64], x2 = ip[128], x3 = ip[192];
  float qv = q[b * 64 + lane];
  float bv = nmb[lane];
  float c0 = bv, c1 = bv, c2 = bv, c3 = bv;
  #pragma unroll
  for (int k = 0; k < 64; ++k) {
    float w = nmw[k * 64 + lane];
    c0 = fmaf(rdlane(x0, k), w, c0); c1 = fmaf(rdlane(x1, k), w, c1);
    c2 = fmaf(rdlane(x2, k), w, c2); c3 = fmaf(rdlane(x3, k), w, c3);
  }
  float qa = 0.f;
  #pragma unroll
  for (int k = 0; k < 64; ++k) {
    float w = nmw[(64 + k) * 64 + lane];
    qa = fmaf(rdlane(qv, k), w, qa);
  }
  float* op = out + (size_t)r0 * 64 + lane;
  op[0] = c0 + qa; op[64] = c1 + qa; op[128] = c2 + qa; op[192] = c3 + qa;
}

// ---------------- final scoring ----------------
__global__ void k_score(const float* __restrict__ entx, const float* __restrict__ q,
                        const int* __restrict__ batch,
                        fp m1w, fp m1b, fp m2w, fp m2b,
                        float* __restrict__ out) {
  int b = blockIdx.x / kNEG, n = blockIdx.x % kNEG;
  int t = batch[(b * kNEG + n) * 3 + 1];
  int j = threadIdx.x;  // 0..127
  __shared__ float gv[128];
  __shared__ float red[2];
  gv[j] = (j < 64) ? entx[((size_t)b * kN + t) * 64 + j] : q[b * 64 + (j - 64)];
  __syncthreads();
  float acc = m1b[j];
  #pragma unroll 16
  for (int k = 0; k < 128; ++k)
    acc = fmaf(gv[k], m1w[k * 128 + j], acc);
  float h = fmaxf(acc, 0.f) * m2w[j];
  h = wave_sum64(h);
  if ((j & 63) == 0) red[j >> 6] = h;
  __syncthreads();
  if (j == 0) out[b * kNEG + n] = red[0] + red[1] + m2b[0];
}

// ---------------- host ----------------
static inline void fill_async(float* p, float v, int n, hipStream_t s) {
  int nb = (n + 255) / 256;
  if (nb > 4096) nb = 4096;
  hipLaunchKernelGGL(k_fill, dim3(nb), dim3(256), 0, s, p, v, n);
}

extern "C" void kernel_launch(void* const* d_in, const int* in_sizes, int n_in,
                              void* d_out, int out_size, void* d_ws, size_t ws_size,
                              hipStream_t stream) {
  const int* edge_src  = (const int*)d_in[0];
  const int* edge_dst  = (const int*)d_in[1];
  const int* edge_type = (const int*)d_in[2];
  const int* rel_src   = (const int*)d_in[3];
  const int* rel_dst   = (const int*)d_in[4];
  const int* rel_etype = (const int*)d_in[5];
  const int* batch     = (const int*)d_in[6];
  fp e1p1w = (fp)d_in[7],  e1p1b = (fp)d_in[8],  e1p2w = (fp)d_in[9],  e1p2b = (fp)d_in[10];
  fp e1lw  = (fp)d_in[11], e1lb  = (fp)d_in[12], e1lns = (fp)d_in[13], e1lnb = (fp)d_in[14];
  fp e2p1w = (fp)d_in[15], e2p1b = (fp)d_in[16], e2p2w = (fp)d_in[17], e2p2b = (fp)d_in[18];
  fp e2lw  = (fp)d_in[19], e2lb  = (fp)d_in[20], e2lns = (fp)d_in[21], e2lnb = (fp)d_in[22];
  fp e2m1w = (fp)d_in[23], e2m1b = (fp)d_in[24], e2m2w = (fp)d_in[25], e2m2b = (fp)d_in[26];
  fp rp1w  = (fp)d_in[27], rp1b  = (fp)d_in[28], rp2w  = (fp)d_in[29], rp2b  = (fp)d_in[30];
  fp rlw   = (fp)d_in[31], rlb   = (fp)d_in[32], rlns  = (fp)d_in[33], rlnb  = (fp)d_in[34];
  fp nmw   = (fp)d_in[35], nmb   = (fp)d_in[36];

  float* ws = (float*)d_ws;
  float* rel_x     = ws;                         // 65536
  float* rel_h     = rel_x + 65536;              // 65536
  float* q         = rel_h + 65536;              // 256
  float* node_reps = q + 256;                    // 2,560,000
  float* gateN     = node_reps + 2560000;        // 2,560,000 (aliased as gateR in entity phases)
  float* ent_x     = gateN + 2560000;            // 2,560,000
  float* ent_agg   = ent_x + 2560000;            // 2,560,000 (rel_agg aliases front)
  float* gateR     = gateN;
  float* rel_agg   = ent_agg;
  int*   iws       = (int*)(ent_agg + 2560000);
  int2*  ent_edges = (int2*)iws;                 // 200000 int2 = 400000 ints
  int2*  rel_edges = (int2*)(iws + 400000);      // 4*80000 int2 = 640000 ints
  int*   ent_cnt   = iws + 400000 + 640000;      // 10000
  int*   ent_start = ent_cnt + 10000;            // 10001
  int*   ent_cur   = ent_start + 10001;          // 10001
  int*   rel_cnt   = ent_cur + 10001;            // 4*256
  int*   rel_start = rel_cnt + 4 * 256;          // 4*257
  int*   rel_cur   = rel_start + 4 * 257;        // 4*257

  const int nRelRows = kB * kR;   // 1024
  const int nEntRows = kB * kN;   // 40000

  // ---- CSR build (once per call) ----
  hipLaunchKernelGGL(k_zero_i, dim3((10000 + 255) / 256), dim3(256), 0, stream, ent_cnt, 10000);
  hipLaunchKernelGGL(k_hist, dim3((kE + 255) / 256), dim3(256), 0, stream, edge_dst, kE, ent_cnt);
  hipLaunchKernelGGL(k_scan, dim3(1), dim3(256), 0, stream, ent_cnt, ent_start, ent_cur, 10000);
  hipLaunchKernelGGL(k_fill_csr, dim3((kE + 255) / 256), dim3(256), 0, stream,
                     edge_src, edge_dst, edge_type, kE, ent_cur, ent_edges);
  for (int g = 0; g < 4; ++g) {
    hipLaunchKernelGGL(k_zero_i, dim3(1), dim3(256), 0, stream, rel_cnt + g * 256, 256);
    hipLaunchKernelGGL(k_hist, dim3((kER + 255) / 256), dim3(256), 0, stream,
                       rel_dst + (size_t)g * kER, kER, rel_cnt + g * 256);
    hipLaunchKernelGGL(k_scan, dim3(1), dim3(256), 0, stream,
                       rel_cnt + g * 256, rel_start + g * 257, rel_cur + g * 257, 256);
    hipLaunchKernelGGL(k_fill_csr, dim3((kER + 255) / 256), dim3(256), 0, stream,
                       rel_src + (size_t)g * kER, rel_dst + (size_t)g * kER,
                       rel_etype + (size_t)g * kER, kER, rel_cur + g * 257, rel_edges + (size_t)g * kER);
  }

  // ---- init ----
  fill_async(node_reps, 1.0f, kB * kN * kD, stream);
  fill_async(rel_x, 0.0f, kB * kR * kD, stream);
  hipLaunchKernelGGL(k_add_row, dim3(1), dim3(256), 0, stream, rel_x, batch, (const float*)nullptr, kR, 0);

  for (int i = 0; i < kL; ++i) {
    fill_async(rel_h, 0.0f, kB * kR * kD, stream);
    for (int g = 0; g < 4; ++g) {
      int pg = g * kL + i;
      hipLaunchKernelGGL(k_mlp4, dim3(nEntRows / 16), dim3(256), 0, stream,
                         node_reps, rp1w + (size_t)pg * 4096, rp1b + (size_t)pg * 64,
                         rp2w + (size_t)pg * 4096, rp2b + (size_t)pg * 64, gateN, nEntRows);
      hipLaunchKernelGGL(k_gather_rel, dim3(nRelRows), dim3(256), 0, stream,
                         rel_x, gateN, rel_start + g * 257, rel_edges + (size_t)g * kER,
                         batch, rel_agg);
      hipLaunchKernelGGL(k_conv4, dim3(nRelRows / 16), dim3(256), 0, stream,
                         rel_x, rel_agg, rlw + (size_t)pg * 8192, rlb + (size_t)pg * 64,
                         rlns + (size_t)pg * 64, rlnb + (size_t)pg * 64, rel_h, nRelRows);
    }
    hipLaunchKernelGGL(k_axpy, dim3(kB * kR * kD / 256), dim3(256), 0, stream, rel_x, rel_h, kB * kR * kD);

    if (i == 0) {
      hipLaunchKernelGGL(k_get_q, dim3(1), dim3(256), 0, stream, q, rel_x, batch);
      fill_async(ent_x, 0.0f, kB * kN * kD, stream);
      hipLaunchKernelGGL(k_add_row, dim3(1), dim3(256), 0, stream, ent_x, batch, q, kN, 1);
      for (int j = 0; j < kL; ++j) {
        hipLaunchKernelGGL(k_mlp4, dim3(nRelRows / 16), dim3(256), 0, stream,
                           rel_x, e1p1w + (size_t)j * 4096, e1p1b + (size_t)j * 64,
                           e1p2w + (size_t)j * 4096, e1p2b + (size_t)j * 64, gateR, nRelRows);
        hipLaunchKernelGGL(k_gather_ent, dim3(nEntRows / 4), dim3(256), 0, stream,
                           ent_x, gateR, ent_start, ent_edges, q, batch, ent_agg);
        hipLaunchKernelGGL(k_conv4, dim3(nEntRows / 16), dim3(256), 0, stream,
                           ent_x, ent_agg, e1lw + (size_t)j * 8192, e1lb + (size_t)j * 64,
                           e1lns + (size_t)j * 64, e1lnb + (size_t)j * 64, ent_x, nEntRows);
      }
      hipLaunchKernelGGL(k_nodeup4, dim3(nEntRows / 16), dim3(256), 0, stream,
                         ent_x, q, nmw, nmb, node_reps, nEntRows);
    }
  }

  // ---- entity_bf with e2 params, then scoring ----
  hipLaunchKernelGGL(k_get_q, dim3(1), dim3(256), 0, stream, q, rel_x, batch);
  fill_async(ent_x, 0.0f, kB * kN * kD, stream);
  hipLaunchKernelGGL(k_add_row, dim3(1), dim3(256), 0, stream, ent_x, batch, q, kN, 1);
  for (int j = 0; j < kL; ++j) {
    hipLaunchKernelGGL(k_mlp4, dim3(nRelRows / 16), dim3(256), 0, stream,
                       rel_x, e2p1w + (size_t)j * 4096, e2p1b + (size_t)j * 64,
                       e2p2w + (size_t)j * 4096, e2p2b + (size_t)j * 64, gateR, nRelRows);
    hipLaunchKernelGGL(k_gather_ent, dim3(nEntRows / 4), dim3(256), 0, stream,
                       ent_x, gateR, ent_start, ent_edges, q, batch, ent_agg);
    hipLaunchKernelGGL(k_conv4, dim3(nEntRows / 16), dim3(256), 0, stream,
                       ent_x, ent_agg, e2lw + (size_t)j * 8192, e2lb + (size_t)j * 64,
                       e2lns + (size_t)j * 64, e2lnb + (size_t)j * 64, ent_x, nEntRows);
  }
  hipLaunchKernelGGL(k_score, dim3(kB * kNEG), dim3(128), 0, stream,
                     ent_x, q, batch, e2m1w, e2m1b, e2m2w, e2m2b, (float*)d_out);
}

// Round 4
// 2451.938 us; speedup vs baseline: 2.5481x; 1.0112x over previous
//
#include <hip/hip_runtime.h>

constexpr int kB   = 4;
constexpr int kNEG = 33;
constexpr int kN   = 10000;
constexpr int kR   = 256;
constexpr int kD   = 64;
constexpr int kL   = 6;
constexpr int kE   = 200000;
constexpr int kER  = 80000;

typedef const float* fp;

__device__ __forceinline__ float rdlane(float v, int l) {
  return __uint_as_float(__builtin_amdgcn_readlane(__float_as_uint(v), l));
}
__device__ __forceinline__ float wave_sum64(float v) {
  #pragma unroll
  for (int o = 32; o > 0; o >>= 1) v += __shfl_xor(v, o, 64);
  return v;
}

// ---------------- utility ----------------
__global__ void k_fill(float* __restrict__ p, float v, int n) {
  int i = blockIdx.x * blockDim.x + threadIdx.x;
  int stride = gridDim.x * blockDim.x;
  for (; i < n; i += stride) p[i] = v;
}
__global__ void k_zero_i(int* __restrict__ p, int n) {
  int i = blockIdx.x * blockDim.x + threadIdx.x;
  if (i < n) p[i] = 0;
}
__global__ void k_add_row(float* __restrict__ dst, const int* __restrict__ batch) {
  int tid = threadIdx.x;
  int b = tid >> 6, d = tid & 63;
  int row = batch[b * kNEG * 3 + 2];
  dst[((size_t)b * kR + row) * 64 + d] += 1.0f;
}
__global__ void k_get_q(float* __restrict__ q, const float* __restrict__ relx,
                        const int* __restrict__ batch) {
  int tid = threadIdx.x;
  int b = tid >> 6, d = tid & 63;
  int r0 = batch[b * kNEG * 3 + 2];
  q[b * 64 + d] = relx[((size_t)b * kR + r0) * 64 + d];
}

// ---------------- CSR build ----------------
__global__ void k_hist(const int* __restrict__ dst, int ne, int* __restrict__ cnt) {
  int i = blockIdx.x * blockDim.x + threadIdx.x;
  if (i < ne) atomicAdd(&cnt[dst[i]], 1);
}
__global__ void k_scan(const int* __restrict__ cnt, int* __restrict__ start,
                       int* __restrict__ cursor, int n) {
  __shared__ int part[256];
  int t = threadIdx.x;
  int chunk = (n + 255) / 256;
  int lo = t * chunk, hi = min(lo + chunk, n);
  int s = 0;
  for (int i = lo; i < hi; ++i) s += cnt[i];
  part[t] = s;
  __syncthreads();
  if (t == 0) { int run = 0; for (int i = 0; i < 256; ++i) { int v = part[i]; part[i] = run; run += v; } }
  __syncthreads();
  int run = part[t];
  for (int i = lo; i < hi; ++i) { start[i] = run; cursor[i] = run; run += cnt[i]; }
  if (t == 255) start[n] = run;
}
__global__ void k_fill_csr(const int* __restrict__ src, const int* __restrict__ dst,
                           const int* __restrict__ et, int ne,
                           int* __restrict__ cursor, int2* __restrict__ out) {
  int i = blockIdx.x * blockDim.x + threadIdx.x;
  if (i < ne) {
    int p = atomicAdd(&cursor[dst[i]], 1);
    out[p] = make_int2(src[i], et[i]);
  }
}

// ---------------- 4-row MLP (one weight set): out = relu(in@W1+b1)@W2+b2 ----------------
__global__ void k_mlp4(const float* __restrict__ in, fp W1, fp b1, fp W2, fp b2,
                       float* __restrict__ out, int rows) {
  int wid = (blockIdx.x * blockDim.x + threadIdx.x) >> 6;
  int lane = threadIdx.x & 63;
  int r0 = wid * 4;
  if (r0 >= rows) return;
  const float* ip = in + (size_t)r0 * 64 + lane;
  float x0 = ip[0], x1 = ip[64], x2 = ip[128], x3 = ip[192];
  float bv = b1[lane];
  float a0 = bv, a1 = bv, a2 = bv, a3 = bv;
  #pragma unroll
  for (int k = 0; k < 64; ++k) {
    float w = W1[k * 64 + lane];
    a0 = fmaf(rdlane(x0, k), w, a0); a1 = fmaf(rdlane(x1, k), w, a1);
    a2 = fmaf(rdlane(x2, k), w, a2); a3 = fmaf(rdlane(x3, k), w, a3);
  }
  a0 = fmaxf(a0, 0.f); a1 = fmaxf(a1, 0.f); a2 = fmaxf(a2, 0.f); a3 = fmaxf(a3, 0.f);
  bv = b2[lane];
  float c0 = bv, c1 = bv, c2 = bv, c3 = bv;
  #pragma unroll
  for (int k = 0; k < 64; ++k) {
    float w = W2[k * 64 + lane];
    c0 = fmaf(rdlane(a0, k), w, c0); c1 = fmaf(rdlane(a1, k), w, c1);
    c2 = fmaf(rdlane(a2, k), w, c2); c3 = fmaf(rdlane(a3, k), w, c3);
  }
  float* op = out + (size_t)r0 * 64 + lane;
  op[0] = c0; op[64] = c1; op[128] = c2; op[192] = c3;
}

// ---------------- all-groups 4-row MLP for rel gates (blockIdx.y = g) ----------------
__global__ void k_mlp_allg(const float* __restrict__ in, fp p1w, fp p1b, fp p2w, fp p2b,
                           int layer, float* __restrict__ out) {
  int g = blockIdx.y;
  int pg = g * kL + layer;
  int wid = (blockIdx.x * blockDim.x + threadIdx.x) >> 6;
  int lane = threadIdx.x & 63;
  int r0 = wid * 4;
  if (r0 >= kB * kN) return;
  fp W1 = p1w + (size_t)pg * 4096;
  fp W2 = p2w + (size_t)pg * 4096;
  const float* ip = in + (size_t)r0 * 64 + lane;
  float x0 = ip[0], x1 = ip[64], x2 = ip[128], x3 = ip[192];
  float bv = p1b[pg * 64 + lane];
  float a0 = bv, a1 = bv, a2 = bv, a3 = bv;
  #pragma unroll
  for (int k = 0; k < 64; ++k) {
    float w = W1[k * 64 + lane];
    a0 = fmaf(rdlane(x0, k), w, a0); a1 = fmaf(rdlane(x1, k), w, a1);
    a2 = fmaf(rdlane(x2, k), w, a2); a3 = fmaf(rdlane(x3, k), w, a3);
  }
  a0 = fmaxf(a0, 0.f); a1 = fmaxf(a1, 0.f); a2 = fmaxf(a2, 0.f); a3 = fmaxf(a3, 0.f);
  bv = p2b[pg * 64 + lane];
  float c0 = bv, c1 = bv, c2 = bv, c3 = bv;
  #pragma unroll
  for (int k = 0; k < 64; ++k) {
    float w = W2[k * 64 + lane];
    c0 = fmaf(rdlane(a0, k), w, c0); c1 = fmaf(rdlane(a1, k), w, c1);
    c2 = fmaf(rdlane(a2, k), w, c2); c3 = fmaf(rdlane(a3, k), w, c3);
  }
  float* op = out + (size_t)g * kB * kN * 64 + (size_t)r0 * 64 + lane;
  op[0] = c0; op[64] = c1; op[128] = c2; op[192] = c3;
}

// ---------------- i=0 rel specials ----------------
// gate0[g][d]: MLP applied to the all-ones row (node_reps == 1 at i=0)
__global__ void k_gate0(fp p1w, fp p1b, fp p2w, fp p2b, float* __restrict__ gate0) {
  int g = threadIdx.x >> 6, lane = threadIdx.x & 63;
  int pg = g * kL;   // layer 0
  float a = p1b[pg * 64 + lane];
  #pragma unroll
  for (int k = 0; k < 64; ++k) a += p1w[(size_t)pg * 4096 + k * 64 + lane];
  a = fmaxf(a, 0.f);
  float c = p2b[pg * 64 + lane];
  #pragma unroll
  for (int k = 0; k < 64; ++k)
    c = fmaf(rdlane(a, k), p2w[(size_t)pg * 4096 + k * 64 + lane], c);
  gate0[g * 64 + lane] = c;
}
// agg[g][b][r][d] = gate0[g][d] * |{e in list(g,r): src==r0[b]}| + (r==r0[b])
__global__ void k_rel_agg0(const int* __restrict__ rel_start, const int2* __restrict__ rel_edges,
                           const int* __restrict__ batch, const float* __restrict__ gate0,
                           float* __restrict__ agg) {
  int wid = (blockIdx.x * blockDim.x + threadIdx.x) >> 6;  // g*1024 + b*256 + r
  int lane = threadIdx.x & 63;
  int g = wid >> 10, rem = wid & 1023, b = rem >> 8, r = rem & 255;
  int r0 = batch[b * kNEG * 3 + 2];
  const int* start = rel_start + g * 257;
  const int2* edges = rel_edges + (size_t)g * kER;
  int s0 = start[r], s1 = start[r + 1];
  int cnt = 0;
  for (int base = s0; base < s1; base += 64) {
    int e = base + lane;
    bool m = false;
    if (e < s1) m = (edges[e].x == r0);
    cnt += (int)__popcll(__ballot(m));
  }
  agg[(size_t)wid * 64 + lane] = gate0[g * 64 + lane] * (float)cnt + ((r == r0) ? 1.f : 0.f);
}

// ---------------- rel gather (dense gates), blockIdx.y = g ----------------
__global__ void k_gather_rel_all(const float* __restrict__ x, const float* __restrict__ gateN,
                                 const int* __restrict__ rel_start, const int2* __restrict__ rel_edges,
                                 const int* __restrict__ batch, float* __restrict__ agg) {
  int g = blockIdx.y;
  const float* gate = gateN + (size_t)g * kB * kN * 64;
  const int* start = rel_start + g * 257;
  const int2* edges = rel_edges + (size_t)g * kER;
  int blk = blockIdx.x;              // b*kR + r
  int b = blk >> 8, r = blk & 255;
  int w = threadIdx.x >> 6, lane = threadIdx.x & 63;
  const float* xb = x + (size_t)b * kR * 64 + lane;
  const float* gb = gate + (size_t)b * kN * 64 + lane;
  int s0 = start[r], s1 = start[r + 1];
  int len = s1 - s0;
  int per = (len + 3) >> 2;
  int e0 = s0 + w * per, e1 = min(e0 + per, s1);
  float acc = 0.f;
  #pragma unroll 4
  for (int e = e0; e < e1; ++e) {
    int2 se = edges[e];
    acc = fmaf(xb[(size_t)se.x * 64], gb[(size_t)se.y * 64], acc);
  }
  __shared__ float red[4][64];
  red[w][lane] = acc;
  __syncthreads();
  if (w == 0) {
    float a = red[0][lane] + red[1][lane] + red[2][lane] + red[3][lane];
    int r0 = batch[b * kNEG * 3 + 2];
    if (r == r0) a += 1.0f;
    agg[((size_t)g * kB * kR + blk) * 64 + lane] = a;
  }
}

// ---------------- fused rel conv over 4 groups + residual (in place) ----------------
__global__ void k_conv_rel(float* __restrict__ rel_x, const float* __restrict__ agg,
                           fp rlw, fp rlb, fp rlns, fp rlnb, int layer) {
  int wid = (blockIdx.x * blockDim.x + threadIdx.x) >> 6;  // b*256+r
  if (wid >= kB * kR) return;
  int lane = threadIdx.x & 63;
  float xr = rel_x[(size_t)wid * 64 + lane];
  float total = 0.f;
  for (int g = 0; g < 4; ++g) {
    int pg = g * kL + layer;
    float ag = agg[((size_t)g * kB * kR + wid) * 64 + lane];
    fp w1 = rlw + (size_t)pg * 8192;
    float o = rlb[pg * 64 + lane];
    #pragma unroll
    for (int k = 0; k < 64; ++k) o = fmaf(rdlane(xr, k), w1[k * 64 + lane], o);
    #pragma unroll
    for (int k = 0; k < 64; ++k) o = fmaf(rdlane(ag, k), w1[(64 + k) * 64 + lane], o);
    float m = wave_sum64(o) * (1.f / 64.f); float c = o - m;
    float v = wave_sum64(c * c) * (1.f / 64.f);
    total += fmaxf(c * rsqrtf(v + 1e-5f) * rlns[pg * 64 + lane] + rlnb[pg * 64 + lane], 0.f);
  }
  rel_x[(size_t)wid * 64 + lane] = xr + total;
}

// ---------------- fused entity layer: gather + boundary + conv + LN + residual ----------------
// one wave per node n, 4 batches per wave; reads xcur, writes xnext (double buffer)
template<bool FIRST>
__global__ void k_ent_layer(const float* __restrict__ xcur, float* __restrict__ xnext,
                            const float* __restrict__ gateR,
                            const int* __restrict__ start, const int2* __restrict__ edges,
                            const float* __restrict__ q, const int* __restrict__ batch,
                            fp lw, fp lb, fp lns, fp lnb) {
  int n = (blockIdx.x * blockDim.x + threadIdx.x) >> 6;
  if (n >= kN) return;
  int lane = threadIdx.x & 63;
  int h0[4]; float qv[4];
  #pragma unroll
  for (int b = 0; b < 4; ++b) { h0[b] = batch[b * kNEG * 3]; qv[b] = q[b * 64 + lane]; }
  float a0 = 0.f, a1 = 0.f, a2 = 0.f, a3 = 0.f;
  int s0 = start[n], s1 = start[n + 1];
  for (int e = s0; e < s1; ++e) {
    int2 se = edges[e];
    const float* gp = gateR + (size_t)se.y * 64 + lane;
    if (FIRST) {
      if (se.x == h0[0]) a0 = fmaf(qv[0], gp[0],     a0);
      if (se.x == h0[1]) a1 = fmaf(qv[1], gp[16384], a1);
      if (se.x == h0[2]) a2 = fmaf(qv[2], gp[32768], a2);
      if (se.x == h0[3]) a3 = fmaf(qv[3], gp[49152], a3);
    } else {
      const float* xp = xcur + (size_t)se.x * 64 + lane;
      a0 = fmaf(xp[0],       gp[0],     a0);
      a1 = fmaf(xp[640000],  gp[16384], a1);
      a2 = fmaf(xp[1280000], gp[32768], a2);
      a3 = fmaf(xp[1920000], gp[49152], a3);
    }
  }
  if (n == h0[0]) a0 += qv[0];
  if (n == h0[1]) a1 += qv[1];
  if (n == h0[2]) a2 += qv[2];
  if (n == h0[3]) a3 += qv[3];
  float x0, x1, x2, x3;
  if (FIRST) {
    x0 = (n == h0[0]) ? qv[0] : 0.f; x1 = (n == h0[1]) ? qv[1] : 0.f;
    x2 = (n == h0[2]) ? qv[2] : 0.f; x3 = (n == h0[3]) ? qv[3] : 0.f;
  } else {
    const float* xp = xcur + (size_t)n * 64 + lane;
    x0 = xp[0]; x1 = xp[640000]; x2 = xp[1280000]; x3 = xp[1920000];
  }
  float bv = lb[lane];
  float o0 = bv, o1 = bv, o2 = bv, o3 = bv;
  #pragma unroll
  for (int k = 0; k < 64; ++k) {
    float w = lw[k * 64 + lane];
    o0 = fmaf(rdlane(x0, k), w, o0); o1 = fmaf(rdlane(x1, k), w, o1);
    o2 = fmaf(rdlane(x2, k), w, o2); o3 = fmaf(rdlane(x3, k), w, o3);
  }
  #pragma unroll
  for (int k = 0; k < 64; ++k) {
    float w = lw[(64 + k) * 64 + lane];
    o0 = fmaf(rdlane(a0, k), w, o0); o1 = fmaf(rdlane(a1, k), w, o1);
    o2 = fmaf(rdlane(a2, k), w, o2); o3 = fmaf(rdlane(a3, k), w, o3);
  }
  float s = lns[lane], t = lnb[lane];
  float* yp = xnext + (size_t)n * 64 + lane;
  { float m = wave_sum64(o0) * (1.f/64.f); float c = o0 - m;
    float v = wave_sum64(c*c) * (1.f/64.f);
    yp[0] = x0 + fmaxf(c * rsqrtf(v + 1e-5f) * s + t, 0.f); }
  { float m = wave_sum64(o1) * (1.f/64.f); float c = o1 - m;
    float v = wave_sum64(c*c) * (1.f/64.f);
    yp[640000] = x1 + fmaxf(c * rsqrtf(v + 1e-5f) * s + t, 0.f); }
  { float m = wave_sum64(o2) * (1.f/64.f); float c = o2 - m;
    float v = wave_sum64(c*c) * (1.f/64.f);
    yp[1280000] = x2 + fmaxf(c * rsqrtf(v + 1e-5f) * s + t, 0.f); }
  { float m = wave_sum64(o3) * (1.f/64.f); float c = o3 - m;
    float v = wave_sum64(c*c) * (1.f/64.f);
    yp[1920000] = x3 + fmaxf(c * rsqrtf(v + 1e-5f) * s + t, 0.f); }
}

// ---------------- node_reps = concat(ent_x, q)@nmw + nmb (4-row) ----------------
__global__ void k_nodeup4(const float* __restrict__ x, const float* __restrict__ q,
                          fp nmw, fp nmb, float* __restrict__ out) {
  int wid = (blockIdx.x * blockDim.x + threadIdx.x) >> 6;
  int lane = threadIdx.x & 63;
  int r0 = wid * 4;
  if (r0 >= kB * kN) return;
  int b = r0 / kN;
  const float* ip = x + (size_t)(r0 % kN) * 64 + (size_t)b * kN * 64 + lane;
  // note: x layout is [b][n][d]; r0 groups of 4 never straddle b (kN%4==0)
  float x0 = ip[0], x1 = ip[64], x2 = ip[128], x3 = ip[192];
  float qv = q[b * 64 + lane];
  float bv = nmb[lane];
  float c0 = bv, c1 = bv, c2 = bv, c3 = bv;
  #pragma unroll
  for (int k = 0; k < 64; ++k) {
    float w = nmw[k * 64 + lane];
    c0 = fmaf(rdlane(x0, k), w, c0); c1 = fmaf(rdlane(x1, k), w, c1);
    c2 = fmaf(rdlane(x2, k), w, c2); c3 = fmaf(rdlane(x3, k), w, c3);
  }
  float qa = 0.f;
  #pragma unroll
  for (int k = 0; k < 64; ++k)
    qa = fmaf(rdlane(qv, k), nmw[(64 + k) * 64 + lane], qa);
  float* op = out + (size_t)r0 * 64 + lane;
  op[0] = c0 + qa; op[64] = c1 + qa; op[128] = c2 + qa; op[192] = c3 + qa;
}

// ---------------- final scoring ----------------
__global__ void k_score(const float* __restrict__ entx, const float* __restrict__ q,
                        const int* __restrict__ batch,
                        fp m1w, fp m1b, fp m2w, fp m2b,
                        float* __restrict__ out) {
  int b = blockIdx.x / kNEG, n = blockIdx.x % kNEG;
  int t = batch[(b * kNEG + n) * 3 + 1];
  int j = threadIdx.x;  // 0..127
  __shared__ float gv[128];
  __shared__ float red[2];
  gv[j] = (j < 64) ? entx[((size_t)b * kN + t) * 64 + j] : q[b * 64 + (j - 64)];
  __syncthreads();
  float acc = m1b[j];
  #pragma unroll 16
  for (int k = 0; k < 128; ++k)
    acc = fmaf(gv[k], m1w[k * 128 + j], acc);
  float h = fmaxf(acc, 0.f) * m2w[j];
  h = wave_sum64(h);
  if ((j & 63) == 0) red[j >> 6] = h;
  __syncthreads();
  if (j == 0) out[b * kNEG + n] = red[0] + red[1] + m2b[0];
}

// ---------------- host ----------------
extern "C" void kernel_launch(void* const* d_in, const int* in_sizes, int n_in,
                              void* d_out, int out_size, void* d_ws, size_t ws_size,
                              hipStream_t stream) {
  const int* edge_src  = (const int*)d_in[0];
  const int* edge_dst  = (const int*)d_in[1];
  const int* edge_type = (const int*)d_in[2];
  const int* rel_src   = (const int*)d_in[3];
  const int* rel_dst   = (const int*)d_in[4];
  const int* rel_etype = (const int*)d_in[5];
  const int* batch     = (const int*)d_in[6];
  fp e1p1w = (fp)d_in[7],  e1p1b = (fp)d_in[8],  e1p2w = (fp)d_in[9],  e1p2b = (fp)d_in[10];
  fp e1lw  = (fp)d_in[11], e1lb  = (fp)d_in[12], e1lns = (fp)d_in[13], e1lnb = (fp)d_in[14];
  fp e2p1w = (fp)d_in[15], e2p1b = (fp)d_in[16], e2p2w = (fp)d_in[17], e2p2b = (fp)d_in[18];
  fp e2lw  = (fp)d_in[19], e2lb  = (fp)d_in[20], e2lns = (fp)d_in[21], e2lnb = (fp)d_in[22];
  fp e2m1w = (fp)d_in[23], e2m1b = (fp)d_in[24], e2m2w = (fp)d_in[25], e2m2b = (fp)d_in[26];
  fp rp1w  = (fp)d_in[27], rp1b  = (fp)d_in[28], rp2w  = (fp)d_in[29], rp2b  = (fp)d_in[30];
  fp rlw   = (fp)d_in[31], rlb   = (fp)d_in[32], rlns  = (fp)d_in[33], rlnb  = (fp)d_in[34];
  fp nmw   = (fp)d_in[35], nmb   = (fp)d_in[36];

  float* ws = (float*)d_ws;
  float* rel_x     = ws;                           // 65,536
  float* q         = rel_x + 65536;                // 256
  float* gateR     = q + 256;                      // 65,536
  float* gate0     = gateR + 65536;                // 256
  float* rel_agg   = gate0 + 256;                  // 4*65,536 = 262,144
  float* node_reps = rel_agg + 262144;             // 2,560,000
  float* gateN     = node_reps + 2560000;          // 4*2,560,000 = 10,240,000
  float* ent_xa    = gateN + 10240000;             // 2,560,000
  float* ent_xb    = ent_xa + 2560000;             // 2,560,000
  int*   iws       = (int*)(ent_xb + 2560000);
  int2*  ent_edges = (int2*)iws;                   // 400,000 ints
  int2*  rel_edges = (int2*)(iws + 400000);        // 640,000 ints
  int*   ent_cnt   = iws + 400000 + 640000;        // 10,000
  int*   ent_start = ent_cnt + 10000;              // 10,001
  int*   ent_cur   = ent_start + 10001;            // 10,001
  int*   rel_cnt   = ent_cur + 10001;              // 1,024
  int*   rel_start = rel_cnt + 1024;               // 1,028
  int*   rel_cur   = rel_start + 1028;             // 1,028

  // ---- CSR build ----
  k_zero_i<<<40, 256, 0, stream>>>(ent_cnt, 10000);
  k_hist<<<(kE + 255) / 256, 256, 0, stream>>>(edge_dst, kE, ent_cnt);
  k_scan<<<1, 256, 0, stream>>>(ent_cnt, ent_start, ent_cur, 10000);
  k_fill_csr<<<(kE + 255) / 256, 256, 0, stream>>>(edge_src, edge_dst, edge_type, kE, ent_cur, ent_edges);
  for (int g = 0; g < 4; ++g) {
    k_zero_i<<<1, 256, 0, stream>>>(rel_cnt + g * 256, 256);
    k_hist<<<(kER + 255) / 256, 256, 0, stream>>>(rel_dst + (size_t)g * kER, kER, rel_cnt + g * 256);
    k_scan<<<1, 256, 0, stream>>>(rel_cnt + g * 256, rel_start + g * 257, rel_cur + g * 257, 256);
    k_fill_csr<<<(kER + 255) / 256, 256, 0, stream>>>(
        rel_src + (size_t)g * kER, rel_dst + (size_t)g * kER,
        rel_etype + (size_t)g * kER, kER, rel_cur + g * 257, rel_edges + (size_t)g * kER);
  }

  // ---- rel_x = one-hot boundary ----
  k_fill<<<256, 256, 0, stream>>>(rel_x, 0.f, kB * kR * kD);
  k_add_row<<<1, 256, 0, stream>>>(rel_x, batch);

  // ---- i = 0 (degenerate: node_reps == ones) ----
  k_gate0<<<1, 256, 0, stream>>>(rp1w, rp1b, rp2w, rp2b, gate0);
  k_rel_agg0<<<1024, 256, 0, stream>>>(rel_start, rel_edges, batch, gate0, rel_agg);
  k_conv_rel<<<256, 256, 0, stream>>>(rel_x, rel_agg, rlw, rlb, rlns, rlnb, 0);

  // ---- entity_bf with e1 params -> node_reps ----
  k_get_q<<<1, 256, 0, stream>>>(q, rel_x, batch);
  {
    float* cur = ent_xa; float* nxt = ent_xb;
    for (int j = 0; j < kL; ++j) {
      k_mlp4<<<64, 256, 0, stream>>>(rel_x, e1p1w + (size_t)j * 4096, e1p1b + (size_t)j * 64,
                                     e1p2w + (size_t)j * 4096, e1p2b + (size_t)j * 64, gateR, kB * kR);
      if (j == 0)
        k_ent_layer<true><<<2500, 256, 0, stream>>>(cur, nxt, gateR, ent_start, ent_edges, q, batch,
            e1lw + (size_t)j * 8192, e1lb + (size_t)j * 64, e1lns + (size_t)j * 64, e1lnb + (size_t)j * 64);
      else
        k_ent_layer<false><<<2500, 256, 0, stream>>>(cur, nxt, gateR, ent_start, ent_edges, q, batch,
            e1lw + (size_t)j * 8192, e1lb + (size_t)j * 64, e1lns + (size_t)j * 64, e1lnb + (size_t)j * 64);
      float* tmp = cur; cur = nxt; nxt = tmp;
    }
    // after 6 layers, result is in `cur` (== ent_xa)
    k_nodeup4<<<2500, 256, 0, stream>>>(cur, q, nmw, nmb, node_reps);
  }

  // ---- i = 1..5 ----
  for (int i = 1; i < kL; ++i) {
    k_mlp_allg<<<dim3(2500, 4), 256, 0, stream>>>(node_reps, rp1w, rp1b, rp2w, rp2b, i, gateN);
    k_gather_rel_all<<<dim3(1024, 4), 256, 0, stream>>>(rel_x, gateN, rel_start, rel_edges, batch, rel_agg);
    k_conv_rel<<<256, 256, 0, stream>>>(rel_x, rel_agg, rlw, rlb, rlns, rlnb, i);
  }

  // ---- entity_bf with e2 params + scoring ----
  k_get_q<<<1, 256, 0, stream>>>(q, rel_x, batch);
  {
    float* cur = ent_xa; float* nxt = ent_xb;
    for (int j = 0; j < kL; ++j) {
      k_mlp4<<<64, 256, 0, stream>>>(rel_x, e2p1w + (size_t)j * 4096, e2p1b + (size_t)j * 64,
                                     e2p2w + (size_t)j * 4096, e2p2b + (size_t)j * 64, gateR, kB * kR);
      if (j == 0)
        k_ent_layer<true><<<2500, 256, 0, stream>>>(cur, nxt, gateR, ent_start, ent_edges, q, batch,
            e2lw + (size_t)j * 8192, e2lb + (size_t)j * 64, e2lns + (size_t)j * 64, e2lnb + (size_t)j * 64);
      else
        k_ent_layer<false><<<2500, 256, 0, stream>>>(cur, nxt, gateR, ent_start, ent_edges, q, batch,
            e2lw + (size_t)j * 8192, e2lb + (size_t)j * 64, e2lns + (size_t)j * 64, e2lnb + (size_t)j * 64);
      float* tmp = cur; cur = nxt; nxt = tmp;
    }
    k_score<<<kB * kNEG, 128, 0, stream>>>(cur, q, batch, e2m1w, e2m1b, e2m2w, e2m2b, (float*)d_out);
  }
}

// Round 6
// 1555.771 us; speedup vs baseline: 4.0160x; 1.5760x over previous
//
#include <hip/hip_runtime.h>

constexpr int kB   = 4;
constexpr int kNEG = 33;
constexpr int kN   = 10000;
constexpr int kR   = 256;
constexpr int kD   = 64;
constexpr int kL   = 6;
constexpr int kE   = 200000;
constexpr int kER  = 80000;

typedef const float* fp;

__device__ __forceinline__ float rdlane(float v, int l) {
  return __uint_as_float(__builtin_amdgcn_readlane(__float_as_uint(v), l));
}
__device__ __forceinline__ float wave_sum64(float v) {
  #pragma unroll
  for (int o = 32; o > 0; o >>= 1) v += __shfl_xor(v, o, 64);
  return v;
}

// ---------------- utility ----------------
__global__ void k_fill(float* __restrict__ p, float v, int n) {
  int i = blockIdx.x * blockDim.x + threadIdx.x;
  int stride = gridDim.x * blockDim.x;
  for (; i < n; i += stride) p[i] = v;
}
// grid-stride zero (round-5 bug: non-strided version silently under-covered,
// leaving rel_cnt poisoned -> OOB writes in k_fill_csr_rel -> device abort)
__global__ void k_zero_i(int* __restrict__ p, int n) {
  int i = blockIdx.x * blockDim.x + threadIdx.x;
  int stride = gridDim.x * blockDim.x;
  for (; i < n; i += stride) p[i] = 0;
}
__global__ void k_add_row(float* __restrict__ dst, const int* __restrict__ batch) {
  int tid = threadIdx.x;
  int b = tid >> 6, d = tid & 63;
  int row = batch[b * kNEG * 3 + 2];
  dst[((size_t)b * kR + row) * 64 + d] += 1.0f;
}
__global__ void k_get_q(float* __restrict__ q, const float* __restrict__ relx,
                        const int* __restrict__ batch) {
  int tid = threadIdx.x;
  int b = tid >> 6, d = tid & 63;
  int r0 = batch[b * kNEG * 3 + 2];
  q[b * 64 + d] = relx[((size_t)b * kR + r0) * 64 + d];
}

// ---------------- CSR build ----------------
__global__ void k_hist(const int* __restrict__ dst, int ne, int* __restrict__ cnt) {
  int i = blockIdx.x * blockDim.x + threadIdx.x;
  if (i < ne) atomicAdd(&cnt[dst[i]], 1);
}
__global__ void k_hist_rel(const int* __restrict__ rel_dst, int* __restrict__ cnt) {
  int g = blockIdx.y;
  int i = blockIdx.x * blockDim.x + threadIdx.x;
  if (i < kER) atomicAdd(&cnt[g * 256 + rel_dst[(size_t)g * kER + i]], 1);
}
// per-block exclusive scan; blockIdx.x selects segment
__global__ void k_scan_multi(const int* __restrict__ cnt, int* __restrict__ start,
                             int* __restrict__ cursor, int n, int cstride, int sstride) {
  const int* c = cnt + (size_t)blockIdx.x * cstride;
  int* st = start + (size_t)blockIdx.x * sstride;
  int* cu = cursor + (size_t)blockIdx.x * sstride;
  __shared__ int part[256];
  int t = threadIdx.x;
  int chunk = (n + 255) / 256;
  int lo = t * chunk, hi = min(lo + chunk, n);
  int s = 0;
  for (int i = lo; i < hi; ++i) s += c[i];
  part[t] = s;
  __syncthreads();
  if (t == 0) { int run = 0; for (int i = 0; i < 256; ++i) { int v = part[i]; part[i] = run; run += v; } }
  __syncthreads();
  int run = part[t];
  for (int i = lo; i < hi; ++i) { st[i] = run; cu[i] = run; run += c[i]; }
  if (t == 255) st[n] = run;
}
__global__ void k_fill_csr(const int* __restrict__ src, const int* __restrict__ dst,
                           const int* __restrict__ et, int ne,
                           int* __restrict__ cursor, int2* __restrict__ out) {
  int i = blockIdx.x * blockDim.x + threadIdx.x;
  if (i < ne) {
    int p = atomicAdd(&cursor[dst[i]], 1);
    out[p] = make_int2(src[i], et[i]);
  }
}
__global__ void k_fill_csr_rel(const int* __restrict__ src, const int* __restrict__ dst,
                               const int* __restrict__ et,
                               int* __restrict__ cursor, int2* __restrict__ out) {
  int g = blockIdx.y;
  int i = blockIdx.x * blockDim.x + threadIdx.x;
  if (i < kER) {
    int p = atomicAdd(&cursor[g * 257 + dst[(size_t)g * kER + i]], 1);
    out[(size_t)g * kER + p] = make_int2(src[(size_t)g * kER + i], et[(size_t)g * kER + i]);
  }
}

// ---------------- rel-gate MLP for entity phase: all 6 layers, row per wave ----------------
__global__ void __launch_bounds__(256) k_mlp_rel6(
    const float* __restrict__ in, fp p1w, fp p1b, fp p2w, fp p2b,
    float* __restrict__ out) {
  int j = blockIdx.y;                               // layer
  int row = blockIdx.x * 4 + (threadIdx.x >> 6);    // 256 blocks * 4 waves = 1024 rows
  int lane = threadIdx.x & 63;
  fp W1 = p1w + (size_t)j * 4096;
  fp W2 = p2w + (size_t)j * 4096;
  float xv = in[(size_t)row * 64 + lane];
  float a = p1b[j * 64 + lane];
  float wbuf[8];
  #pragma unroll
  for (int kk = 0; kk < 64; kk += 8) {
    #pragma unroll
    for (int u = 0; u < 8; ++u) wbuf[u] = W1[(kk + u) * 64 + lane];
    #pragma unroll
    for (int u = 0; u < 8; ++u) a = fmaf(rdlane(xv, kk + u), wbuf[u], a);
  }
  a = fmaxf(a, 0.f);
  float c = p2b[j * 64 + lane];
  #pragma unroll
  for (int kk = 0; kk < 64; kk += 8) {
    #pragma unroll
    for (int u = 0; u < 8; ++u) wbuf[u] = W2[(kk + u) * 64 + lane];
    #pragma unroll
    for (int u = 0; u < 8; ++u) c = fmaf(rdlane(a, kk + u), wbuf[u], c);
  }
  out[((size_t)j * kB * kR + row) * 64 + lane] = c;
}

// ---------------- all-groups 4-row MLP for rel gates over node_reps ----------------
__global__ void __launch_bounds__(256) k_mlp_allg(
    const float* __restrict__ in, fp p1w, fp p1b, fp p2w, fp p2b,
    int layer, float* __restrict__ out) {
  int g = blockIdx.y;
  int pg = g * kL + layer;
  int wid = (blockIdx.x * blockDim.x + threadIdx.x) >> 6;
  int lane = threadIdx.x & 63;
  int r0 = wid * 4;
  if (r0 >= kB * kN) return;
  fp W1 = p1w + (size_t)pg * 4096;
  fp W2 = p2w + (size_t)pg * 4096;
  const float* ip = in + (size_t)r0 * 64 + lane;
  float x0 = ip[0], x1 = ip[64], x2 = ip[128], x3 = ip[192];
  float bv = p1b[pg * 64 + lane];
  float a0 = bv, a1 = bv, a2 = bv, a3 = bv;
  float wbuf[4];
  #pragma unroll
  for (int kk = 0; kk < 64; kk += 4) {
    #pragma unroll
    for (int u = 0; u < 4; ++u) wbuf[u] = W1[(kk + u) * 64 + lane];
    #pragma unroll
    for (int u = 0; u < 4; ++u) {
      int k = kk + u; float w = wbuf[u];
      a0 = fmaf(rdlane(x0, k), w, a0); a1 = fmaf(rdlane(x1, k), w, a1);
      a2 = fmaf(rdlane(x2, k), w, a2); a3 = fmaf(rdlane(x3, k), w, a3);
    }
  }
  a0 = fmaxf(a0, 0.f); a1 = fmaxf(a1, 0.f); a2 = fmaxf(a2, 0.f); a3 = fmaxf(a3, 0.f);
  bv = p2b[pg * 64 + lane];
  float c0 = bv, c1 = bv, c2 = bv, c3 = bv;
  #pragma unroll
  for (int kk = 0; kk < 64; kk += 4) {
    #pragma unroll
    for (int u = 0; u < 4; ++u) wbuf[u] = W2[(kk + u) * 64 + lane];
    #pragma unroll
    for (int u = 0; u < 4; ++u) {
      int k = kk + u; float w = wbuf[u];
      c0 = fmaf(rdlane(a0, k), w, c0); c1 = fmaf(rdlane(a1, k), w, c1);
      c2 = fmaf(rdlane(a2, k), w, c2); c3 = fmaf(rdlane(a3, k), w, c3);
    }
  }
  float* op = out + (size_t)g * kB * kN * 64 + (size_t)r0 * 64 + lane;
  op[0] = c0; op[64] = c1; op[128] = c2; op[192] = c3;
}

// ---------------- i=0 rel specials ----------------
__global__ void k_gate0(fp p1w, fp p1b, fp p2w, fp p2b, float* __restrict__ gate0) {
  int g = threadIdx.x >> 6, lane = threadIdx.x & 63;
  int pg = g * kL;
  float a = p1b[pg * 64 + lane];
  #pragma unroll
  for (int k = 0; k < 64; ++k) a += p1w[(size_t)pg * 4096 + k * 64 + lane];
  a = fmaxf(a, 0.f);
  float c = p2b[pg * 64 + lane];
  #pragma unroll
  for (int k = 0; k < 64; ++k)
    c = fmaf(rdlane(a, k), p2w[(size_t)pg * 4096 + k * 64 + lane], c);
  gate0[g * 64 + lane] = c;
}
__global__ void k_rel_agg0(const int* __restrict__ rel_start, const int2* __restrict__ rel_edges,
                           const int* __restrict__ batch, const float* __restrict__ gate0,
                           float* __restrict__ agg) {
  int wid = (blockIdx.x * blockDim.x + threadIdx.x) >> 6;  // g*1024 + b*256 + r
  int lane = threadIdx.x & 63;
  int g = wid >> 10, rem = wid & 1023, b = rem >> 8, r = rem & 255;
  int r0 = batch[b * kNEG * 3 + 2];
  const int* start = rel_start + g * 257;
  const int2* edges = rel_edges + (size_t)g * kER;
  int s0 = start[r], s1 = start[r + 1];
  int cnt = 0;
  for (int base = s0; base < s1; base += 64) {
    int e = base + lane;
    bool m = false;
    if (e < s1) m = (edges[e].x == r0);
    cnt += (int)__popcll(__ballot(m));
  }
  agg[(size_t)wid * 64 + lane] = gate0[g * 64 + lane] * (float)cnt + ((r == r0) ? 1.f : 0.f);
}

// ---------------- rel gather (dense gates), blockIdx.y = g ----------------
__global__ void __launch_bounds__(256) k_gather_rel_all(
    const float* __restrict__ x, const float* __restrict__ gateN,
    const int* __restrict__ rel_start, const int2* __restrict__ rel_edges,
    const int* __restrict__ batch, float* __restrict__ agg) {
  int g = blockIdx.y;
  const float* gate = gateN + (size_t)g * kB * kN * 64;
  const int* start = rel_start + g * 257;
  const int2* edges = rel_edges + (size_t)g * kER;
  int blk = blockIdx.x;              // b*kR + r
  int b = blk >> 8, r = blk & 255;
  int w = threadIdx.x >> 6, lane = threadIdx.x & 63;
  const float* xb = x + (size_t)b * kR * 64 + lane;
  const float* gb = gate + (size_t)b * kN * 64 + lane;
  int s0 = start[r], s1 = start[r + 1];
  int len = s1 - s0;
  int per = (len + 3) >> 2;
  int e0 = s0 + w * per, e1 = min(e0 + per, s1);
  float acc = 0.f;
  int2 se;
  if (e0 < e1) se = edges[e0];
  for (int e = e0; e < e1; ++e) {
    int2 cur = se;
    if (e + 1 < e1) se = edges[e + 1];
    acc = fmaf(xb[(size_t)cur.x * 64], gb[(size_t)cur.y * 64], acc);
  }
  __shared__ float red[4][64];
  red[w][lane] = acc;
  __syncthreads();
  if (w == 0) {
    float a = red[0][lane] + red[1][lane] + red[2][lane] + red[3][lane];
    int r0 = batch[b * kNEG * 3 + 2];
    if (r == r0) a += 1.0f;
    agg[((size_t)g * kB * kR + blk) * 64 + lane] = a;
  }
}

// ---------------- rel conv: one block per row, wave = group, 8-deep load pipeline ----------------
__global__ void __launch_bounds__(256) k_conv_rel2(
    float* __restrict__ rel_x, const float* __restrict__ agg,
    fp rlw, fp rlb, fp rlns, fp rlnb, int layer) {
  int row = blockIdx.x;               // b*256+r (1024 blocks)
  int g = threadIdx.x >> 6, lane = threadIdx.x & 63;
  int pg = g * kL + layer;
  float xr = rel_x[(size_t)row * 64 + lane];
  float ag = agg[((size_t)g * kB * kR + row) * 64 + lane];
  fp w1 = rlw + (size_t)pg * 8192;
  float o = rlb[pg * 64 + lane];
  float wbuf[8];
  #pragma unroll
  for (int kk = 0; kk < 128; kk += 8) {
    #pragma unroll
    for (int u = 0; u < 8; ++u) wbuf[u] = w1[(kk + u) * 64 + lane];
    #pragma unroll
    for (int u = 0; u < 8; ++u) {
      int k = kk + u;
      float xv = (k < 64) ? rdlane(xr, k) : rdlane(ag, k - 64);
      o = fmaf(xv, wbuf[u], o);
    }
  }
  float m = wave_sum64(o) * (1.f / 64.f);
  float c = o - m;
  float v = wave_sum64(c * c) * (1.f / 64.f);
  float y = fmaxf(c * rsqrtf(v + 1e-5f) * rlns[pg * 64 + lane] + rlnb[pg * 64 + lane], 0.f);
  __shared__ float red[4][64];
  red[g][lane] = y;
  __syncthreads();
  if (g == 0)
    rel_x[(size_t)row * 64 + lane] = xr + red[0][lane] + red[1][lane] + red[2][lane] + red[3][lane];
}

// ---------------- fused entity layer ----------------
template<bool FIRST>
__global__ void __launch_bounds__(256) k_ent_layer2(
    const float* __restrict__ xcur, float* __restrict__ xnext,
    const float* __restrict__ gateL,
    const int* __restrict__ start, const int2* __restrict__ edges,
    const float* __restrict__ q, const int* __restrict__ batch,
    fp lw, fp lb, fp lns, fp lnb) {
  int n = (blockIdx.x * blockDim.x + threadIdx.x) >> 6;
  if (n >= kN) return;
  int lane = threadIdx.x & 63;
  int h0[4]; float qv[4];
  #pragma unroll
  for (int b = 0; b < 4; ++b) { h0[b] = batch[b * kNEG * 3]; qv[b] = q[b * 64 + lane]; }
  float a0 = 0.f, a1 = 0.f, a2 = 0.f, a3 = 0.f;
  int s0 = start[n], s1 = start[n + 1];
  int2 se;
  if (s0 < s1) se = edges[s0];
  for (int e = s0; e < s1; ++e) {
    int2 cur = se;
    if (e + 1 < s1) se = edges[e + 1];
    const float* gp = gateL + (size_t)cur.y * 64 + lane;
    if (FIRST) {
      if (cur.x == h0[0]) a0 = fmaf(qv[0], gp[0],     a0);
      if (cur.x == h0[1]) a1 = fmaf(qv[1], gp[16384], a1);
      if (cur.x == h0[2]) a2 = fmaf(qv[2], gp[32768], a2);
      if (cur.x == h0[3]) a3 = fmaf(qv[3], gp[49152], a3);
    } else {
      const float* xp = xcur + (size_t)cur.x * 64 + lane;
      a0 = fmaf(xp[0],       gp[0],     a0);
      a1 = fmaf(xp[640000],  gp[16384], a1);
      a2 = fmaf(xp[1280000], gp[32768], a2);
      a3 = fmaf(xp[1920000], gp[49152], a3);
    }
  }
  if (n == h0[0]) a0 += qv[0];
  if (n == h0[1]) a1 += qv[1];
  if (n == h0[2]) a2 += qv[2];
  if (n == h0[3]) a3 += qv[3];
  float x0, x1, x2, x3;
  if (FIRST) {
    x0 = (n == h0[0]) ? qv[0] : 0.f; x1 = (n == h0[1]) ? qv[1] : 0.f;
    x2 = (n == h0[2]) ? qv[2] : 0.f; x3 = (n == h0[3]) ? qv[3] : 0.f;
  } else {
    const float* xp = xcur + (size_t)n * 64 + lane;
    x0 = xp[0]; x1 = xp[640000]; x2 = xp[1280000]; x3 = xp[1920000];
  }
  float bv = lb[lane];
  float o0 = bv, o1 = bv, o2 = bv, o3 = bv;
  float wbuf[8];
  #pragma unroll
  for (int kk = 0; kk < 128; kk += 8) {
    #pragma unroll
    for (int u = 0; u < 8; ++u) wbuf[u] = lw[(kk + u) * 64 + lane];
    #pragma unroll
    for (int u = 0; u < 8; ++u) {
      int k = kk + u; float w = wbuf[u];
      if (k < 64) {
        o0 = fmaf(rdlane(x0, k), w, o0); o1 = fmaf(rdlane(x1, k), w, o1);
        o2 = fmaf(rdlane(x2, k), w, o2); o3 = fmaf(rdlane(x3, k), w, o3);
      } else {
        o0 = fmaf(rdlane(a0, k - 64), w, o0); o1 = fmaf(rdlane(a1, k - 64), w, o1);
        o2 = fmaf(rdlane(a2, k - 64), w, o2); o3 = fmaf(rdlane(a3, k - 64), w, o3);
      }
    }
  }
  float s = lns[lane], t = lnb[lane];
  float* yp = xnext + (size_t)n * 64 + lane;
  { float m = wave_sum64(o0) * (1.f/64.f); float c = o0 - m;
    float v = wave_sum64(c*c) * (1.f/64.f);
    yp[0] = x0 + fmaxf(c * rsqrtf(v + 1e-5f) * s + t, 0.f); }
  { float m = wave_sum64(o1) * (1.f/64.f); float c = o1 - m;
    float v = wave_sum64(c*c) * (1.f/64.f);
    yp[640000] = x1 + fmaxf(c * rsqrtf(v + 1e-5f) * s + t, 0.f); }
  { float m = wave_sum64(o2) * (1.f/64.f); float c = o2 - m;
    float v = wave_sum64(c*c) * (1.f/64.f);
    yp[1280000] = x2 + fmaxf(c * rsqrtf(v + 1e-5f) * s + t, 0.f); }
  { float m = wave_sum64(o3) * (1.f/64.f); float c = o3 - m;
    float v = wave_sum64(c*c) * (1.f/64.f);
    yp[1920000] = x3 + fmaxf(c * rsqrtf(v + 1e-5f) * s + t, 0.f); }
}

// ---------------- node_reps = concat(ent_x, q)@nmw + nmb ----------------
__global__ void __launch_bounds__(256) k_nodeup4(
    const float* __restrict__ x, const float* __restrict__ q,
    fp nmw, fp nmb, float* __restrict__ out) {
  int wid = (blockIdx.x * blockDim.x + threadIdx.x) >> 6;
  int lane = threadIdx.x & 63;
  int r0 = wid * 4;
  if (r0 >= kB * kN) return;
  int b = r0 / kN;
  const float* ip = x + (size_t)r0 * 64 + lane;
  float x0 = ip[0], x1 = ip[64], x2 = ip[128], x3 = ip[192];
  float qv = q[b * 64 + lane];
  float bv = nmb[lane];
  float c0 = bv, c1 = bv, c2 = bv, c3 = bv;
  float wbuf[4];
  #pragma unroll
  for (int kk = 0; kk < 64; kk += 4) {
    #pragma unroll
    for (int u = 0; u < 4; ++u) wbuf[u] = nmw[(kk + u) * 64 + lane];
    #pragma unroll
    for (int u = 0; u < 4; ++u) {
      int k = kk + u; float w = wbuf[u];
      c0 = fmaf(rdlane(x0, k), w, c0); c1 = fmaf(rdlane(x1, k), w, c1);
      c2 = fmaf(rdlane(x2, k), w, c2); c3 = fmaf(rdlane(x3, k), w, c3);
    }
  }
  float qa = 0.f;
  #pragma unroll
  for (int k = 0; k < 64; ++k)
    qa = fmaf(rdlane(qv, k), nmw[(64 + k) * 64 + lane], qa);
  float* op = out + (size_t)r0 * 64 + lane;
  op[0] = c0 + qa; op[64] = c1 + qa; op[128] = c2 + qa; op[192] = c3 + qa;
}

// ---------------- final scoring ----------------
__global__ void k_score(const float* __restrict__ entx, const float* __restrict__ q,
                        const int* __restrict__ batch,
                        fp m1w, fp m1b, fp m2w, fp m2b,
                        float* __restrict__ out) {
  int b = blockIdx.x / kNEG, n = blockIdx.x % kNEG;
  int t = batch[(b * kNEG + n) * 3 + 1];
  int j = threadIdx.x;  // 0..127
  __shared__ float gv[128];
  __shared__ float red[2];
  gv[j] = (j < 64) ? entx[((size_t)b * kN + t) * 64 + j] : q[b * 64 + (j - 64)];
  __syncthreads();
  float acc = m1b[j];
  #pragma unroll 16
  for (int k = 0; k < 128; ++k)
    acc = fmaf(gv[k], m1w[k * 128 + j], acc);
  float h = fmaxf(acc, 0.f) * m2w[j];
  h = wave_sum64(h);
  if ((j & 63) == 0) red[j >> 6] = h;
  __syncthreads();
  if (j == 0) out[b * kNEG + n] = red[0] + red[1] + m2b[0];
}

// ---------------- host ----------------
extern "C" void kernel_launch(void* const* d_in, const int* in_sizes, int n_in,
                              void* d_out, int out_size, void* d_ws, size_t ws_size,
                              hipStream_t stream) {
  const int* edge_src  = (const int*)d_in[0];
  const int* edge_dst  = (const int*)d_in[1];
  const int* edge_type = (const int*)d_in[2];
  const int* rel_src   = (const int*)d_in[3];
  const int* rel_dst   = (const int*)d_in[4];
  const int* rel_etype = (const int*)d_in[5];
  const int* batch     = (const int*)d_in[6];
  fp e1p1w = (fp)d_in[7],  e1p1b = (fp)d_in[8],  e1p2w = (fp)d_in[9],  e1p2b = (fp)d_in[10];
  fp e1lw  = (fp)d_in[11], e1lb  = (fp)d_in[12], e1lns = (fp)d_in[13], e1lnb = (fp)d_in[14];
  fp e2p1w = (fp)d_in[15], e2p1b = (fp)d_in[16], e2p2w = (fp)d_in[17], e2p2b = (fp)d_in[18];
  fp e2lw  = (fp)d_in[19], e2lb  = (fp)d_in[20], e2lns = (fp)d_in[21], e2lnb = (fp)d_in[22];
  fp e2m1w = (fp)d_in[23], e2m1b = (fp)d_in[24], e2m2w = (fp)d_in[25], e2m2b = (fp)d_in[26];
  fp rp1w  = (fp)d_in[27], rp1b  = (fp)d_in[28], rp2w  = (fp)d_in[29], rp2b  = (fp)d_in[30];
  fp rlw   = (fp)d_in[31], rlb   = (fp)d_in[32], rlns  = (fp)d_in[33], rlnb  = (fp)d_in[34];
  fp nmw   = (fp)d_in[35], nmb   = (fp)d_in[36];

  float* ws = (float*)d_ws;
  float* rel_x     = ws;                           // 65,536
  float* q         = rel_x + 65536;                // 256
  float* gate0     = q + 256;                      // 256
  float* gateR6    = gate0 + 256;                  // 6*65,536 = 393,216
  float* rel_agg   = gateR6 + 393216;              // 4*65,536 = 262,144
  float* node_reps = rel_agg + 262144;             // 2,560,000
  float* gateN     = node_reps + 2560000;          // 4*2,560,000 = 10,240,000
  float* ent_xa    = gateN + 10240000;             // 2,560,000
  float* ent_xb    = ent_xa + 2560000;             // 2,560,000
  int*   iws       = (int*)(ent_xb + 2560000);
  int2*  ent_edges = (int2*)iws;                   // 400,000 ints
  int2*  rel_edges = (int2*)(iws + 400000);        // 640,000 ints
  int*   ent_cnt   = iws + 400000 + 640000;        // 10,000
  int*   ent_start = ent_cnt + 10000;              // 10,001
  int*   ent_cur   = ent_start + 10001;            // 10,001
  int*   rel_cnt   = ent_cur + 10001;              // 1,024
  int*   rel_start = rel_cnt + 1024;               // 4*257 = 1,028
  int*   rel_cur   = rel_start + 1028;             // 1,028

  const int nZero = 10000 + 10001 + 10001 + 1024;  // ent_cnt..rel_cnt inclusive
  // ---- CSR build ----
  k_zero_i<<<(nZero + 255) / 256, 256, 0, stream>>>(ent_cnt, nZero);
  k_hist<<<(kE + 255) / 256, 256, 0, stream>>>(edge_dst, kE, ent_cnt);
  k_hist_rel<<<dim3((kER + 255) / 256, 4), 256, 0, stream>>>(rel_dst, rel_cnt);
  k_scan_multi<<<1, 256, 0, stream>>>(ent_cnt, ent_start, ent_cur, 10000, 0, 0);
  k_scan_multi<<<4, 256, 0, stream>>>(rel_cnt, rel_start, rel_cur, 256, 256, 257);
  k_fill_csr<<<(kE + 255) / 256, 256, 0, stream>>>(edge_src, edge_dst, edge_type, kE, ent_cur, ent_edges);
  k_fill_csr_rel<<<dim3((kER + 255) / 256, 4), 256, 0, stream>>>(rel_src, rel_dst, rel_etype, rel_cur, rel_edges);

  // ---- rel_x = one-hot boundary ----
  k_fill<<<256, 256, 0, stream>>>(rel_x, 0.f, kB * kR * kD);
  k_add_row<<<1, 256, 0, stream>>>(rel_x, batch);

  // ---- i = 0 (node_reps == ones) ----
  k_gate0<<<1, 256, 0, stream>>>(rp1w, rp1b, rp2w, rp2b, gate0);
  k_rel_agg0<<<1024, 256, 0, stream>>>(rel_start, rel_edges, batch, gate0, rel_agg);
  k_conv_rel2<<<1024, 256, 0, stream>>>(rel_x, rel_agg, rlw, rlb, rlns, rlnb, 0);

  // ---- entity_bf with e1 params -> node_reps ----
  k_get_q<<<1, 256, 0, stream>>>(q, rel_x, batch);
  k_mlp_rel6<<<dim3(256, 6), 256, 0, stream>>>(rel_x, e1p1w, e1p1b, e1p2w, e1p2b, gateR6);
  {
    float* cur = ent_xa; float* nxt = ent_xb;
    for (int j = 0; j < kL; ++j) {
      const float* gL = gateR6 + (size_t)j * kB * kR * 64;
      if (j == 0)
        k_ent_layer2<true><<<2500, 256, 0, stream>>>(cur, nxt, gL, ent_start, ent_edges, q, batch,
            e1lw + (size_t)j * 8192, e1lb + (size_t)j * 64, e1lns + (size_t)j * 64, e1lnb + (size_t)j * 64);
      else
        k_ent_layer2<false><<<2500, 256, 0, stream>>>(cur, nxt, gL, ent_start, ent_edges, q, batch,
            e1lw + (size_t)j * 8192, e1lb + (size_t)j * 64, e1lns + (size_t)j * 64, e1lnb + (size_t)j * 64);
      float* tmp = cur; cur = nxt; nxt = tmp;
    }
    k_nodeup4<<<2500, 256, 0, stream>>>(cur, q, nmw, nmb, node_reps);
  }

  // ---- i = 1..5 ----
  for (int i = 1; i < kL; ++i) {
    k_mlp_allg<<<dim3(2500, 4), 256, 0, stream>>>(node_reps, rp1w, rp1b, rp2w, rp2b, i, gateN);
    k_gather_rel_all<<<dim3(1024, 4), 256, 0, stream>>>(rel_x, gateN, rel_start, rel_edges, batch, rel_agg);
    k_conv_rel2<<<1024, 256, 0, stream>>>(rel_x, rel_agg, rlw, rlb, rlns, rlnb, i);
  }

  // ---- entity_bf with e2 params + scoring ----
  k_get_q<<<1, 256, 0, stream>>>(q, rel_x, batch);
  k_mlp_rel6<<<dim3(256, 6), 256, 0, stream>>>(rel_x, e2p1w, e2p1b, e2p2w, e2p2b, gateR6);
  {
    float* cur = ent_xa; float* nxt = ent_xb;
    for (int j = 0; j < kL; ++j) {
      const float* gL = gateR6 + (size_t)j * kB * kR * 64;
      if (j == 0)
        k_ent_layer2<true><<<2500, 256, 0, stream>>>(cur, nxt, gL, ent_start, ent_edges, q, batch,
            e2lw + (size_t)j * 8192, e2lb + (size_t)j * 64, e2lns + (size_t)j * 64, e2lnb + (size_t)j * 64);
      else
        k_ent_layer2<false><<<2500, 256, 0, stream>>>(cur, nxt, gL, ent_start, ent_edges, q, batch,
            e2lw + (size_t)j * 8192, e2lb + (size_t)j * 64, e2lns + (size_t)j * 64, e2lnb + (size_t)j * 64);
      float* tmp = cur; cur = nxt; nxt = tmp;
    }
    k_score<<<kB * kNEG, 128, 0, stream>>>(cur, q, batch, e2m1w, e2m1b, e2m2w, e2m2b, (float*)d_out);
  }
}